// Round 1
// baseline (534.806 us; speedup 1.0000x reference)
//
#include <hip/hip_runtime.h>
#include <hip/hip_bf16.h>

#define TT 4096      // tokens (B*S)
#define DD 768       // model dim
#define FF 3072      // ffn dim
#define EE 8         // experts
#define NSLOT 8192   // 2*TT (top-2)
#define NSLOT_PAD 8320

typedef __attribute__((ext_vector_type(8))) short bf16x8;
typedef __attribute__((ext_vector_type(4))) float f32x4;
typedef const __attribute__((address_space(1))) void* gas1_t;
typedef __attribute__((address_space(3))) void* las3_t;

// ---------------- router: one wave per token ----------------
__global__ void router_kernel(const float* __restrict__ x, const float* __restrict__ rw,
                              int* counts, int* tokE, float* tokW) {
  int wid = threadIdx.x >> 6;
  int lane = threadIdx.x & 63;
  int t = blockIdx.x * 4 + wid;
  const float* xt = x + (size_t)t * DD;
  float acc[EE];
#pragma unroll
  for (int e = 0; e < EE; ++e) acc[e] = 0.f;
#pragma unroll
  for (int i = 0; i < DD / 64; ++i) {
    float xv = xt[i * 64 + lane];
#pragma unroll
    for (int e = 0; e < EE; ++e) acc[e] += xv * rw[e * DD + i * 64 + lane];
  }
#pragma unroll
  for (int off = 32; off > 0; off >>= 1) {
#pragma unroll
    for (int e = 0; e < EE; ++e) acc[e] += __shfl_down(acc[e], off);
  }
  if (lane == 0) {
    // top-2, ties -> lower index (matches jax.lax.top_k)
    float v0 = -1e30f; int e0 = 0;
#pragma unroll
    for (int e = 0; e < EE; ++e) { if (acc[e] > v0) { v0 = acc[e]; e0 = e; } }
    float v1 = -1e30f; int e1 = 0;
#pragma unroll
    for (int e = 0; e < EE; ++e) { if (e != e0 && acc[e] > v1) { v1 = acc[e]; e1 = e; } }
    float w1 = 1.f / (1.f + expf(v0 - v1));  // softmax over [v0, v1]
    float w0 = 1.f - w1;
    tokE[2 * t] = e0; tokE[2 * t + 1] = e1;
    tokW[2 * t] = w0; tokW[2 * t + 1] = w1;
    atomicAdd(&counts[e0], 1);
    atomicAdd(&counts[e1], 1);
  }
}

__global__ void offsets_kernel(const int* counts, int* offs, int* cursor) {
  if (threadIdx.x == 0) {
    int a = 0;
    for (int e = 0; e < EE; ++e) { offs[e] = a; cursor[e] = a; a += counts[e]; }
    offs[EE] = a;
  }
}

__global__ void scatter_kernel(const int* __restrict__ tokE, int* cursor,
                               int* slotTok, int* slotIdx) {
  int t = blockIdx.x * 256 + threadIdx.x;
  if (t >= TT) return;
#pragma unroll
  for (int k = 0; k < 2; ++k) {
    int e = tokE[2 * t + k];
    int s = atomicAdd(&cursor[e], 1);
    slotTok[s] = t;
    slotIdx[2 * t + k] = s;
  }
}

// gather x rows into expert-grouped bf16 matrix Xg[slot][DD]
__global__ void gather_kernel(const float* __restrict__ x, const int* __restrict__ slotTok,
                              __hip_bfloat16* __restrict__ Xg) {
  int s = blockIdx.x;
  int tok = slotTok[s];
  const float* src = x + (size_t)tok * DD;
  __hip_bfloat16* dst = Xg + (size_t)s * DD;
  for (int i = threadIdx.x; i < DD; i += 256) dst[i] = __float2bfloat16(src[i]);
}

// src [K][N] fp32 -> dst [N][K] bf16 (per expert via blockIdx.z), 64x64 LDS tiles
__global__ void transpose_convert_kernel(const float* __restrict__ src,
                                         __hip_bfloat16* __restrict__ dst, int K, int N) {
  __shared__ float tile[64][65];
  const float* S = src + (size_t)blockIdx.z * K * N;
  __hip_bfloat16* Dst = dst + (size_t)blockIdx.z * K * N;
  int k0 = blockIdx.y * 64, n0 = blockIdx.x * 64;
  int tr = threadIdx.x >> 6;
  int tc = threadIdx.x & 63;
#pragma unroll
  for (int i = 0; i < 16; ++i) {
    int r = tr + i * 4;
    tile[r][tc] = S[(size_t)(k0 + r) * N + n0 + tc];
  }
  __syncthreads();
#pragma unroll
  for (int i = 0; i < 16; ++i) {
    int r = tr + i * 4;
    Dst[(size_t)(n0 + r) * K + k0 + tc] = __float2bfloat16(tile[tc][r]);
  }
}

// stage a 128-row x 64-col bf16 tile global->LDS via global_load_lds width 16,
// XOR-16B swizzle (column-block c = s ^ (row&7)) to kill ds_read bank conflicts.
__device__ __forceinline__ void stage_tile_128x64(const short* gsrc, int ldk,
                                                  short* lds, int tid) {
#pragma unroll
  for (int it = 0; it < 4; ++it) {
    int fs = tid + it * 256;          // 16B-slot index 0..1023
    int m = fs >> 3;                  // row 0..127
    int c = (fs & 7) ^ (m & 7);       // swizzled 16B column block
    __builtin_amdgcn_global_load_lds((gas1_t)(gsrc + (size_t)m * ldk + c * 8),
                                     (las3_t)(lds + fs * 8), 16, 0, 0);
  }
}

// GEMM1: H[slot][FF] = gelu(Xg[slot][DD] @ w_fcT + b_fc), grouped per expert
__global__ __launch_bounds__(256) void gemm1_kernel(const __hip_bfloat16* __restrict__ Xg,
    const __hip_bfloat16* __restrict__ wfcT, const float* __restrict__ b_fc,
    __hip_bfloat16* __restrict__ H, const int* __restrict__ offs) {
  __shared__ __align__(16) short As[128 * 64];
  __shared__ __align__(16) short Bs[128 * 64];
  int e = blockIdx.z;
  int off_e = offs[e];
  int n_e = offs[e + 1] - off_e;
  int m_base = blockIdx.y * 128;
  if (m_base >= n_e) return;
  int n0 = blockIdx.x * 128;
  const short* A = (const short*)Xg + (size_t)(off_e + m_base) * DD;
  const short* B = (const short*)wfcT + (size_t)e * FF * DD + (size_t)n0 * DD;
  int tid = threadIdx.x;
  int lane = tid & 63, wid = tid >> 6;
  int l15 = lane & 15, q = lane >> 4;
  int wm = wid & 1, wn = wid >> 1;
  f32x4 acc[4][4] = {};
  for (int kk = 0; kk < DD; kk += 64) {
    stage_tile_128x64(A + kk, DD, As, tid);
    stage_tile_128x64(B + kk, DD, Bs, tid);
    __builtin_amdgcn_s_waitcnt(0);
    __syncthreads();
#pragma unroll
    for (int ks = 0; ks < 2; ++ks) {
      bf16x8 af[4], bfr[4];
#pragma unroll
      for (int mi = 0; mi < 4; ++mi) {
        int m = wm * 64 + mi * 16 + l15;
        int s = ((ks << 2) + q) ^ (m & 7);
        af[mi] = *(const bf16x8*)&As[m * 64 + s * 8];
      }
#pragma unroll
      for (int ni = 0; ni < 4; ++ni) {
        int n = wn * 64 + ni * 16 + l15;
        int s = ((ks << 2) + q) ^ (n & 7);
        bfr[ni] = *(const bf16x8*)&Bs[n * 64 + s * 8];
      }
#pragma unroll
      for (int mi = 0; mi < 4; ++mi)
#pragma unroll
        for (int ni = 0; ni < 4; ++ni)
          acc[mi][ni] = __builtin_amdgcn_mfma_f32_16x16x32_bf16(af[mi], bfr[ni], acc[mi][ni], 0, 0, 0);
    }
    __syncthreads();
  }
  __hip_bfloat16* Hp = H + (size_t)(off_e + m_base) * FF + n0;
#pragma unroll
  for (int mi = 0; mi < 4; ++mi) {
#pragma unroll
    for (int r = 0; r < 4; ++r) {
      int ml = wm * 64 + mi * 16 + q * 4 + r;
      if (m_base + ml < n_e) {
#pragma unroll
        for (int ni = 0; ni < 4; ++ni) {
          int nl = wn * 64 + ni * 16 + l15;
          float v = acc[mi][ni][r] + b_fc[e * FF + n0 + nl];
          v = 0.5f * v * (1.f + erff(v * 0.70710678118654752f));  // exact gelu
          Hp[(size_t)ml * FF + nl] = __float2bfloat16(v);
        }
      }
    }
  }
}

// GEMM2: Yw[slot][DD] = H[slot][FF] @ w_projT + b_proj (fp32 out), grouped per expert
__global__ __launch_bounds__(256) void gemm2_kernel(const __hip_bfloat16* __restrict__ H,
    const __hip_bfloat16* __restrict__ wprojT, const float* __restrict__ b_proj,
    float* __restrict__ Yw, const int* __restrict__ offs) {
  __shared__ __align__(16) short As[128 * 64];
  __shared__ __align__(16) short Bs[128 * 64];
  int e = blockIdx.z;
  int off_e = offs[e];
  int n_e = offs[e + 1] - off_e;
  int m_base = blockIdx.y * 128;
  if (m_base >= n_e) return;
  int n0 = blockIdx.x * 128;
  const short* A = (const short*)H + (size_t)(off_e + m_base) * FF;
  const short* B = (const short*)wprojT + (size_t)e * DD * FF + (size_t)n0 * FF;
  int tid = threadIdx.x;
  int lane = tid & 63, wid = tid >> 6;
  int l15 = lane & 15, q = lane >> 4;
  int wm = wid & 1, wn = wid >> 1;
  f32x4 acc[4][4] = {};
  for (int kk = 0; kk < FF; kk += 64) {
    stage_tile_128x64(A + kk, FF, As, tid);
    stage_tile_128x64(B + kk, FF, Bs, tid);
    __builtin_amdgcn_s_waitcnt(0);
    __syncthreads();
#pragma unroll
    for (int ks = 0; ks < 2; ++ks) {
      bf16x8 af[4], bfr[4];
#pragma unroll
      for (int mi = 0; mi < 4; ++mi) {
        int m = wm * 64 + mi * 16 + l15;
        int s = ((ks << 2) + q) ^ (m & 7);
        af[mi] = *(const bf16x8*)&As[m * 64 + s * 8];
      }
#pragma unroll
      for (int ni = 0; ni < 4; ++ni) {
        int n = wn * 64 + ni * 16 + l15;
        int s = ((ks << 2) + q) ^ (n & 7);
        bfr[ni] = *(const bf16x8*)&Bs[n * 64 + s * 8];
      }
#pragma unroll
      for (int mi = 0; mi < 4; ++mi)
#pragma unroll
        for (int ni = 0; ni < 4; ++ni)
          acc[mi][ni] = __builtin_amdgcn_mfma_f32_16x16x32_bf16(af[mi], bfr[ni], acc[mi][ni], 0, 0, 0);
    }
    __syncthreads();
  }
  float* Yp = Yw + (size_t)(off_e + m_base) * DD + n0;
#pragma unroll
  for (int mi = 0; mi < 4; ++mi) {
#pragma unroll
    for (int r = 0; r < 4; ++r) {
      int ml = wm * 64 + mi * 16 + q * 4 + r;
      if (m_base + ml < n_e) {
#pragma unroll
        for (int ni = 0; ni < 4; ++ni) {
          int nl = wn * 64 + ni * 16 + l15;
          Yp[(size_t)ml * DD + nl] = acc[mi][ni][r] + b_proj[e * DD + n0 + nl];
        }
      }
    }
  }
}

// out[t] = w0 * Y[slot0(t)] + w1 * Y[slot1(t)]
__global__ void combine_kernel(const float* __restrict__ Yw, const int* __restrict__ slotIdx,
                               const float* __restrict__ tokW, float* __restrict__ out) {
  int idx = blockIdx.x * 256 + threadIdx.x;  // TT * (DD/4) total
  int t = idx / (DD / 4);
  int g = idx - t * (DD / 4);
  int s0 = slotIdx[2 * t], s1 = slotIdx[2 * t + 1];
  float w0 = tokW[2 * t], w1 = tokW[2 * t + 1];
  const float4 a = ((const float4*)(Yw + (size_t)s0 * DD))[g];
  const float4 b = ((const float4*)(Yw + (size_t)s1 * DD))[g];
  float4 o;
  o.x = w0 * a.x + w1 * b.x;
  o.y = w0 * a.y + w1 * b.y;
  o.z = w0 * a.z + w1 * b.z;
  o.w = w0 * a.w + w1 * b.w;
  ((float4*)(out + (size_t)t * DD))[g] = o;
}

extern "C" void kernel_launch(void* const* d_in, const int* in_sizes, int n_in,
                              void* d_out, int out_size, void* d_ws, size_t ws_size,
                              hipStream_t stream) {
  const float* x        = (const float*)d_in[0];
  const float* router_w = (const float*)d_in[1];
  const float* w_fc     = (const float*)d_in[2];
  const float* b_fc     = (const float*)d_in[3];
  const float* w_proj   = (const float*)d_in[4];
  const float* b_proj   = (const float*)d_in[5];
  float* out = (float*)d_out;

  char* p = (char*)d_ws;
  auto alloc = [&](size_t bytes) {
    char* r = p;
    p += (bytes + 255) & ~(size_t)255;
    return r;
  };
  __hip_bfloat16* wfcT   = (__hip_bfloat16*)alloc((size_t)EE * FF * DD * 2);  // [E][F][D]
  __hip_bfloat16* wprojT = (__hip_bfloat16*)alloc((size_t)EE * DD * FF * 2);  // [E][D][F]
  __hip_bfloat16* Xg     = (__hip_bfloat16*)alloc((size_t)NSLOT_PAD * DD * 2);
  __hip_bfloat16* H      = (__hip_bfloat16*)alloc((size_t)NSLOT_PAD * FF * 2);
  float*          Yw     = (float*)alloc((size_t)NSLOT_PAD * DD * 4);
  int*   tokE    = (int*)alloc(TT * 2 * 4);
  float* tokW    = (float*)alloc(TT * 2 * 4);
  int*   slotIdx = (int*)alloc(TT * 2 * 4);
  int*   slotTok = (int*)alloc(NSLOT_PAD * 4);
  int*   counts  = (int*)alloc(64);
  int*   offs    = (int*)alloc(64);
  int*   cursor  = (int*)alloc(64);

  hipMemsetAsync(counts, 0, 32, stream);
  router_kernel<<<TT / 4, 256, 0, stream>>>(x, router_w, counts, tokE, tokW);
  offsets_kernel<<<1, 64, 0, stream>>>(counts, offs, cursor);
  scatter_kernel<<<TT / 256, 256, 0, stream>>>(tokE, cursor, slotTok, slotIdx);
  gather_kernel<<<NSLOT, 256, 0, stream>>>(x, slotTok, Xg);
  transpose_convert_kernel<<<dim3(FF / 64, DD / 64, EE), 256, 0, stream>>>(w_fc, wfcT, DD, FF);
  transpose_convert_kernel<<<dim3(DD / 64, FF / 64, EE), 256, 0, stream>>>(w_proj, wprojT, FF, DD);
  gemm1_kernel<<<dim3(FF / 128, TT / 128, EE), 256, 0, stream>>>(Xg, wfcT, b_fc, H, offs);
  gemm2_kernel<<<dim3(DD / 128, TT / 128, EE), 256, 0, stream>>>(H, wprojT, b_proj, Yw, offs);
  combine_kernel<<<TT * (DD / 4) / 256, 256, 0, stream>>>(Yw, slotIdx, tokW, out);
}